// Round 1
// baseline (272.182 us; speedup 1.0000x reference)
//
#include <hip/hip_runtime.h>

// DotProductAttention: B=16, NQ=2048, NK=2048, D=128, DV=128, fp32 in/out.
// Flash-attention style, bf16 MFMA (16x16x32), online softmax, early-exit
// on valid_len (masked tiles contribute exactly 0, matching fp32 reference).

#define B_   16
#define NQ_  2048
#define NK_  2048
#define D_   128
#define DV_  128

typedef __attribute__((ext_vector_type(4))) float          f32x4;
typedef __attribute__((ext_vector_type(8))) __bf16         bf16x8;
typedef __attribute__((ext_vector_type(8))) unsigned short ushort8v;
typedef __attribute__((ext_vector_type(4))) unsigned short ushort4v;

// fp32 -> bf16 round-half-up (unbiased to 2^-25; inputs are normal randoms, no NaN)
__device__ __forceinline__ unsigned short f2bf(float f) {
    unsigned u = __builtin_bit_cast(unsigned, f);
    return (unsigned short)((u + 0x8000u) >> 16);
}
__device__ __forceinline__ float bf2f(unsigned short h) {
    unsigned u = ((unsigned)h) << 16;
    return __builtin_bit_cast(float, u);
}

__global__ __launch_bounds__(256) void attn_fwd(
    const float* __restrict__ Q, const float* __restrict__ K,
    const float* __restrict__ V, const int* __restrict__ vlen,
    float* __restrict__ Out)
{
    // K-tile: 64 keys x 128 d, bf16, row stride 136 (pad 8 -> 16B-aligned rows, banks spread)
    __shared__ unsigned short Kt[64][136];
    // V-tile transposed: 128 dv x 64 keys, bf16, row stride 72
    __shared__ unsigned short Vt[128][72];
    // per-wave P buffer: 16 q x 64 keys, bf16, row stride 72
    __shared__ unsigned short Pb[4][16][72];

    const int tid  = threadIdx.x;
    const int w    = tid >> 6;    // wave id 0..3
    const int L    = tid & 63;    // lane
    const int col  = L & 15;      // MFMA n/col & A-row index
    const int quad = L >> 4;      // MFMA quad
    const int b     = blockIdx.y;
    const int qbase = blockIdx.x * 64;
    const int vl    = vlen[b];
    const int ntiles = (vl + 63) >> 6;   // tiles fully past vl contribute exactly 0

    // ---- Q fragments (A-layout: A[m=col][k=quad*8+j]), pre-scaled by log2(e)/sqrt(128)
    const float qscale = 0.12751743f;
    bf16x8 qf[4];
    {
        const int qrow = qbase + w * 16 + col;
        const float* gQ = Q + ((size_t)b * NQ_ + qrow) * D_;
        #pragma unroll
        for (int c = 0; c < 4; ++c) {
            const float* p = gQ + c * 32 + quad * 8;
            f32x4 a0 = *(const f32x4*)(p);
            f32x4 a1 = *(const f32x4*)(p + 4);
            ushort8v us;
            us[0] = f2bf(a0[0] * qscale); us[1] = f2bf(a0[1] * qscale);
            us[2] = f2bf(a0[2] * qscale); us[3] = f2bf(a0[3] * qscale);
            us[4] = f2bf(a1[0] * qscale); us[5] = f2bf(a1[1] * qscale);
            us[6] = f2bf(a1[2] * qscale); us[7] = f2bf(a1[3] * qscale);
            qf[c] = __builtin_bit_cast(bf16x8, us);
        }
    }

    // ---- accumulators (C-layout: row = quad*4 + r, col = dv chunk*16 + col)
    f32x4 o[8];
    #pragma unroll
    for (int c = 0; c < 8; ++c) o[c] = (f32x4){0.f, 0.f, 0.f, 0.f};
    float m_run[4] = {-1e30f, -1e30f, -1e30f, -1e30f};
    float l_run[4] = {0.f, 0.f, 0.f, 0.f};

    const float* gKb = K + (size_t)b * NK_ * D_;
    const float* gVb = V + (size_t)b * NK_ * DV_;

    for (int kt = 0; kt < ntiles; ++kt) {
        const int k0 = kt * 64;
        __syncthreads();   // previous tile's LDS reads complete before restaging

        // ---- stage K (row-major) and V (transposed) tiles as bf16
        #pragma unroll
        for (int i = 0; i < 8; ++i) {
            int f   = i * 256 + tid;        // 0..2047 float4-chunks
            int row = f >> 5;               // key row 0..63
            int c4  = (f & 31) * 4;         // d / dv column 0..124
            const float* kp = gKb + (size_t)(k0 + row) * D_ + c4;
            f32x4 kv = *(const f32x4*)kp;
            ushort4v ks;
            ks[0] = f2bf(kv[0]); ks[1] = f2bf(kv[1]);
            ks[2] = f2bf(kv[2]); ks[3] = f2bf(kv[3]);
            *(ushort4v*)&Kt[row][c4] = ks;
            const float* vp = gVb + (size_t)(k0 + row) * DV_ + c4;
            f32x4 vv = *(const f32x4*)vp;
            Vt[c4 + 0][row] = f2bf(vv[0]);
            Vt[c4 + 1][row] = f2bf(vv[1]);
            Vt[c4 + 2][row] = f2bf(vv[2]);
            Vt[c4 + 3][row] = f2bf(vv[3]);
        }
        __syncthreads();

        // ---- S-tile = Q K^T (in log2 domain; 16 q x 64 keys per wave)
        f32x4 s[4];
        #pragma unroll
        for (int kc = 0; kc < 4; ++kc) {
            f32x4 acc = (f32x4){0.f, 0.f, 0.f, 0.f};
            const unsigned short* krow = &Kt[kc * 16 + col][quad * 8];
            #pragma unroll
            for (int c = 0; c < 4; ++c) {
                bf16x8 kb = __builtin_bit_cast(bf16x8, *(const ushort8v*)(krow + c * 32));
                acc = __builtin_amdgcn_mfma_f32_16x16x32_bf16(qf[c], kb, acc, 0, 0, 0);
            }
            s[kc] = acc;
        }

        // ---- mask (only the last tile can be partial)
        if (k0 + 64 > vl) {
            #pragma unroll
            for (int kc = 0; kc < 4; ++kc)
                if (k0 + kc * 16 + col >= vl)
                    s[kc] = (f32x4){-1e30f, -1e30f, -1e30f, -1e30f};
        }

        // ---- online softmax: row max over 16 lanes sharing each row
        float mx[4];
        #pragma unroll
        for (int r = 0; r < 4; ++r)
            mx[r] = fmaxf(fmaxf(s[0][r], s[1][r]), fmaxf(s[2][r], s[3][r]));
        #pragma unroll
        for (int off = 1; off < 16; off <<= 1) {
            #pragma unroll
            for (int r = 0; r < 4; ++r)
                mx[r] = fmaxf(mx[r], __shfl_xor(mx[r], off, 64));
        }

        f32x4 al;
        #pragma unroll
        for (int r = 0; r < 4; ++r) {
            float mn = fmaxf(m_run[r], mx[r]);
            al[r] = exp2f(m_run[r] - mn);
            m_run[r] = mn;
        }

        // ---- p = exp2(s - m), write P (bf16) to per-wave LDS, sum rounded p
        float rs[4] = {0.f, 0.f, 0.f, 0.f};
        #pragma unroll
        for (int kc = 0; kc < 4; ++kc) {
            #pragma unroll
            for (int r = 0; r < 4; ++r) {
                unsigned short pb = f2bf(exp2f(s[kc][r] - m_run[r]));
                Pb[w][quad * 4 + r][kc * 16 + col] = pb;
                rs[r] += bf2f(pb);
            }
        }
        #pragma unroll
        for (int off = 1; off < 16; off <<= 1) {
            #pragma unroll
            for (int r = 0; r < 4; ++r)
                rs[r] += __shfl_xor(rs[r], off, 64);
        }
        #pragma unroll
        for (int r = 0; r < 4; ++r)
            l_run[r] = l_run[r] * al[r] + rs[r];
        #pragma unroll
        for (int c = 0; c < 8; ++c) o[c] *= al;

        __syncthreads();   // P visible (C-layout write -> A-layout read)

        // ---- O += P V  (A = P[q=col][key=quad*8+j], B = V[key][dv=chunk*16+col])
        #pragma unroll
        for (int kc2 = 0; kc2 < 2; ++kc2) {
            bf16x8 pa = __builtin_bit_cast(bf16x8,
                *(const ushort8v*)&Pb[w][col][kc2 * 32 + quad * 8]);
            #pragma unroll
            for (int c = 0; c < 8; ++c) {
                bf16x8 vb = __builtin_bit_cast(bf16x8,
                    *(const ushort8v*)&Vt[c * 16 + col][kc2 * 32 + quad * 8]);
                o[c] = __builtin_amdgcn_mfma_f32_16x16x32_bf16(pa, vb, o[c], 0, 0, 0);
            }
        }
    }

    // ---- normalize and store
    f32x4 linv;
    #pragma unroll
    for (int r = 0; r < 4; ++r) linv[r] = 1.0f / l_run[r];
    float* gO = Out + ((size_t)b * NQ_ + qbase + w * 16) * DV_;
    #pragma unroll
    for (int c = 0; c < 8; ++c) {
        #pragma unroll
        for (int r = 0; r < 4; ++r)
            gO[(size_t)(quad * 4 + r) * DV_ + c * 16 + col] = o[c][r] * linv[r];
    }
}

extern "C" void kernel_launch(void* const* d_in, const int* in_sizes, int n_in,
                              void* d_out, int out_size, void* d_ws, size_t ws_size,
                              hipStream_t stream) {
    const float* Q  = (const float*)d_in[0];
    const float* K  = (const float*)d_in[1];
    const float* V  = (const float*)d_in[2];
    const int*   vl = (const int*)d_in[3];
    float* out = (float*)d_out;
    dim3 grid(NQ_ / 64, B_, 1);
    attn_fwd<<<grid, dim3(256, 1, 1), 0, stream>>>(Q, K, V, vl, out);
}

// Round 2
// 154.731 us; speedup vs baseline: 1.7591x; 1.7591x over previous
//
#include <hip/hip_runtime.h>

// DotProductAttention: B=16, NQ=2048, NK=2048, D=128, DV=128, fp32 in/out.
// Flash-attention, bf16 MFMA 16x16x32, online softmax, valid_len early-exit.
// R2: conflict-free LDS (XOR-swizzled V^T, b64/b128 writes), register
// prefetch of next K/V tile, 2 barriers/tile (P round-trip is per-wave).

#define B_   16
#define NQ_  2048
#define NK_  2048
#define D_   128
#define DV_  128

typedef __attribute__((ext_vector_type(4))) float          f32x4;
typedef __attribute__((ext_vector_type(8))) __bf16         bf16x8;
typedef __attribute__((ext_vector_type(8))) unsigned short ushort8v;
typedef __attribute__((ext_vector_type(4))) unsigned short ushort4v;

// fp32 -> bf16 round-half-up (inputs are normal randoms, no NaN)
__device__ __forceinline__ unsigned short f2bf(float f) {
    unsigned u = __builtin_bit_cast(unsigned, f);
    return (unsigned short)((u + 0x8000u) >> 16);
}
__device__ __forceinline__ float bf2f(unsigned short h) {
    unsigned u = ((unsigned)h) << 16;
    return __builtin_bit_cast(float, u);
}

__global__ __launch_bounds__(256, 2) void attn_fwd(
    const float* __restrict__ Q, const float* __restrict__ K,
    const float* __restrict__ V, const int* __restrict__ vlen,
    float* __restrict__ Out)
{
    // K-tile rows: 64 keys x 128 d, stride 136 ushorts (17*16B: b128 reads 2-way free)
    __shared__ unsigned short Kt[64][136];
    // V^T: 128 dv rows x 64 keys, flat, XOR-swizzled at 16B-unit granularity:
    //   element (dv, key) lives at dv*64 + ((key>>3) ^ (dv&7))*8 + (key&7)
    __shared__ unsigned short Vt[128 * 64];
    // per-wave P buffer: 16 q x 64 keys, stride 72 (9*16B: b128 reads 2-way free)
    __shared__ unsigned short Pb[4][16][72];

    const int tid  = threadIdx.x;
    const int w    = tid >> 6;    // wave id 0..3
    const int L    = tid & 63;    // lane
    const int col  = L & 15;      // MFMA n/col & A-row index
    const int quad = L >> 4;      // MFMA quad
    const int b     = blockIdx.y;
    const int qbase = blockIdx.x * 64;
    const int vl    = vlen[b];
    const int ntiles = (vl + 63) >> 6;   // tiles fully past vl contribute exactly 0

    // ---- Q fragments (A-layout: A[m=col][k=quad*8+j]), pre-scaled by log2(e)/sqrt(128)
    const float qscale = 0.12751743f;
    bf16x8 qf[4];
    {
        const int qrow = qbase + w * 16 + col;
        const float* gQ = Q + ((size_t)b * NQ_ + qrow) * D_;
        #pragma unroll
        for (int c = 0; c < 4; ++c) {
            const float* p = gQ + c * 32 + quad * 8;
            f32x4 a0 = *(const f32x4*)(p);
            f32x4 a1 = *(const f32x4*)(p + 4);
            ushort8v us;
            us[0] = f2bf(a0[0] * qscale); us[1] = f2bf(a0[1] * qscale);
            us[2] = f2bf(a0[2] * qscale); us[3] = f2bf(a0[3] * qscale);
            us[4] = f2bf(a1[0] * qscale); us[5] = f2bf(a1[1] * qscale);
            us[6] = f2bf(a1[2] * qscale); us[7] = f2bf(a1[3] * qscale);
            qf[c] = __builtin_bit_cast(bf16x8, us);
        }
    }

    // ---- accumulators (C-layout: row = quad*4 + r, col = dv chunk*16 + col)
    f32x4 o[8];
    #pragma unroll
    for (int c = 0; c < 8; ++c) o[c] = (f32x4){0.f, 0.f, 0.f, 0.f};
    float m_run[4] = {-1e30f, -1e30f, -1e30f, -1e30f};
    float l_run[4] = {0.f, 0.f, 0.f, 0.f};

    const float* gKb = K + (size_t)b * NK_ * D_;
    const float* gVb = V + (size_t)b * NK_ * DV_;

    // ---- prefetch registers: raw fp32 for next tile (convert at write time)
    f32x4 kreg[8];        // K: 8 iters x (1 key-row, 4 d)  [f = i*256+tid]
    float vreg[4][8];     // V: 4 iters x (1 dv, 8 keys)    [item = i*256+tid]

    #define ISSUE_LOADS(K0)                                                  \
        do {                                                                 \
            _Pragma("unroll")                                                \
            for (int i = 0; i < 8; ++i) {                                    \
                int f = i * 256 + tid;                                       \
                int row = f >> 5, c4 = (f & 31) * 4;                         \
                kreg[i] = *(const f32x4*)(gKb + (size_t)((K0) + row) * D_ + c4); \
            }                                                                \
            _Pragma("unroll")                                                \
            for (int i = 0; i < 4; ++i) {                                    \
                int item = i * 256 + tid;                                    \
                int dv = item & 127, kg = item >> 7;                         \
                const float* vp = gVb + (size_t)((K0) + kg * 8) * DV_ + dv;  \
                _Pragma("unroll")                                            \
                for (int j = 0; j < 8; ++j) vreg[i][j] = vp[(size_t)j * DV_];\
            }                                                                \
        } while (0)

    ISSUE_LOADS(0);

    for (int kt = 0; kt < ntiles; ++kt) {
        __syncthreads();   // all waves done reading previous tile's LDS

        // ---- write staged registers to LDS (bf16)
        #pragma unroll
        for (int i = 0; i < 8; ++i) {
            int f = i * 256 + tid;
            int row = f >> 5, c4 = (f & 31) * 4;
            ushort4v ks;
            ks[0] = f2bf(kreg[i][0]); ks[1] = f2bf(kreg[i][1]);
            ks[2] = f2bf(kreg[i][2]); ks[3] = f2bf(kreg[i][3]);
            *(ushort4v*)&Kt[row][c4] = ks;   // b64, conflict-free
        }
        #pragma unroll
        for (int i = 0; i < 4; ++i) {
            int item = i * 256 + tid;
            int dv = item & 127, kg = item >> 7;
            ushort8v us;
            #pragma unroll
            for (int j = 0; j < 8; ++j) us[j] = f2bf(vreg[i][j]);
            *(ushort8v*)&Vt[dv * 64 + (((kg ^ (dv & 7))) << 3)] = us;  // b128, swizzled, conflict-free
        }

        // ---- issue next tile's global loads (overlap with compute below)
        if (kt + 1 < ntiles) ISSUE_LOADS((kt + 1) * 64);

        __syncthreads();   // staged tile visible

        const int k0 = kt * 64;

        // ---- S-tile = Q K^T (log2 domain; 16 q x 64 keys per wave)
        f32x4 s[4];
        #pragma unroll
        for (int kc = 0; kc < 4; ++kc) {
            f32x4 acc = (f32x4){0.f, 0.f, 0.f, 0.f};
            const unsigned short* krow = &Kt[kc * 16 + col][quad * 8];
            #pragma unroll
            for (int c = 0; c < 4; ++c) {
                bf16x8 kb = __builtin_bit_cast(bf16x8, *(const ushort8v*)(krow + c * 32));
                acc = __builtin_amdgcn_mfma_f32_16x16x32_bf16(qf[c], kb, acc, 0, 0, 0);
            }
            s[kc] = acc;
        }

        // ---- mask (only the last tile can be partial)
        if (k0 + 64 > vl) {
            #pragma unroll
            for (int kc = 0; kc < 4; ++kc)
                if (k0 + kc * 16 + col >= vl)
                    s[kc] = (f32x4){-1e30f, -1e30f, -1e30f, -1e30f};
        }

        // ---- online softmax: row max over 16 lanes sharing each q row
        float mx[4];
        #pragma unroll
        for (int r = 0; r < 4; ++r)
            mx[r] = fmaxf(fmaxf(s[0][r], s[1][r]), fmaxf(s[2][r], s[3][r]));
        #pragma unroll
        for (int off = 1; off < 16; off <<= 1) {
            #pragma unroll
            for (int r = 0; r < 4; ++r)
                mx[r] = fmaxf(mx[r], __shfl_xor(mx[r], off, 64));
        }

        f32x4 al;
        #pragma unroll
        for (int r = 0; r < 4; ++r) {
            float mn = fmaxf(m_run[r], mx[r]);
            al[r] = exp2f(m_run[r] - mn);
            m_run[r] = mn;
        }

        // ---- p = exp2(s - m), write P (bf16) to per-wave LDS, sum rounded p
        float rs[4] = {0.f, 0.f, 0.f, 0.f};
        #pragma unroll
        for (int kc = 0; kc < 4; ++kc) {
            #pragma unroll
            for (int r = 0; r < 4; ++r) {
                unsigned short pb = f2bf(exp2f(s[kc][r] - m_run[r]));
                Pb[w][quad * 4 + r][kc * 16 + col] = pb;
                rs[r] += bf2f(pb);
            }
        }
        #pragma unroll
        for (int off = 1; off < 16; off <<= 1) {
            #pragma unroll
            for (int r = 0; r < 4; ++r)
                rs[r] += __shfl_xor(rs[r], off, 64);
        }
        #pragma unroll
        for (int r = 0; r < 4; ++r)
            l_run[r] = l_run[r] * al[r] + rs[r];
        #pragma unroll
        for (int c = 0; c < 8; ++c) o[c] *= al;

        // NOTE: no barrier — Pb[w] is per-wave; DS ops are in-order per wave.

        // ---- O += P V  (A = P[q=col][key=quad*8+j], B = V^T swizzled)
        #pragma unroll
        for (int kc2 = 0; kc2 < 2; ++kc2) {
            bf16x8 pa = __builtin_bit_cast(bf16x8,
                *(const ushort8v*)&Pb[w][col][kc2 * 32 + quad * 8]);
            #pragma unroll
            for (int c = 0; c < 8; ++c) {
                int dv = c * 16 + col;
                int sw = ((kc2 * 4 + quad) ^ (col & 7)) << 3;
                bf16x8 vb = __builtin_bit_cast(bf16x8,
                    *(const ushort8v*)&Vt[dv * 64 + sw]);
                o[c] = __builtin_amdgcn_mfma_f32_16x16x32_bf16(pa, vb, o[c], 0, 0, 0);
            }
        }
    }

    // ---- normalize and store
    f32x4 linv;
    #pragma unroll
    for (int r = 0; r < 4; ++r) linv[r] = 1.0f / l_run[r];
    float* gO = Out + ((size_t)b * NQ_ + qbase + w * 16) * DV_;
    #pragma unroll
    for (int c = 0; c < 8; ++c) {
        #pragma unroll
        for (int r = 0; r < 4; ++r)
            gO[(size_t)(quad * 4 + r) * DV_ + c * 16 + col] = o[c][r] * linv[r];
    }
    #undef ISSUE_LOADS
}

extern "C" void kernel_launch(void* const* d_in, const int* in_sizes, int n_in,
                              void* d_out, int out_size, void* d_ws, size_t ws_size,
                              hipStream_t stream) {
    const float* Q  = (const float*)d_in[0];
    const float* K  = (const float*)d_in[1];
    const float* V  = (const float*)d_in[2];
    const int*   vl = (const int*)d_in[3];
    float* out = (float*)d_out;
    dim3 grid(NQ_ / 64, B_, 1);
    attn_fwd<<<grid, dim3(256, 1, 1), 0, stream>>>(Q, K, V, vl, out);
}